// Round 1
// baseline (1459.079 us; speedup 1.0000x reference)
//
#include <hip/hip_runtime.h>
#include <hip/hip_bf16.h>
#include <float.h>

#define NB 32
#define L 128
#define NTHREADS 256
#define LOGMIN -87.49823f  /* ln(1e-38) */

// ---- mask dtype runtime detection (element [0] is guaranteed true: lens >= 64) ----
__device__ __forceinline__ int mask_mode(const void* p) {
    unsigned int v = ((const unsigned int*)p)[0];
    if (v == 1u) return 1;            // int32 0/1 storage
    if (v == 0x3F800000u) return 2;   // float32 storage
    return 0;                         // byte storage
}
__device__ __forceinline__ bool mask_at(const void* p, int mode, int idx) {
    if (mode == 1) return ((const int*)p)[idx] != 0;
    if (mode == 2) return ((const float*)p)[idx] != 0.0f;
    return ((const unsigned char*)p)[idx] != 0;
}

// strict-upper-triangle index, 0 <= i < j < L
__device__ __forceinline__ int idxu(int i, int j) {
    return i * (L - 1) - (i * (i - 1)) / 2 + (j - i - 1);
}

__device__ __forceinline__ float lse2(float a, float b) {
    return fmaxf(a, b) + log1pf(__expf(-fabsf(a - b)));
}

// ================= Kernel A: per-batch inside/outside DP + span loss =================
__global__ __launch_bounds__(NTHREADS) void tree_dp_kernel(
    const float* __restrict__ logits,   // [B,L,L,2]
    const int*   __restrict__ spans_ind,// [B,L,L]
    const void*  __restrict__ maskspan, // [B,L,L] bool
    double*      __restrict__ ws)
{
    __shared__ float alu[L * (L - 1) / 2];  // strict-upper: sc -> alpha (in place)
    __shared__ float gu [L * (L - 1) / 2];  // strict-upper: sc -> gamma = sc + beta (in place)
    __shared__ float aldiag[L];             // alpha[i,i] == sc[i,i]

    const int b   = blockIdx.x;
    const int tid = threadIdx.x;
    const int mbase = b * L * L;
    const int mode = mask_mode(maskspan);

    // n = lens[b] = sum over j of maskspan[b,0,j]
    int pred = (tid < L) && mask_at(maskspan, mode, mbase + tid);
    const int n = __syncthreads_count(pred);

    const float* lg = logits + (size_t)b * L * L * 2;

    // ---- init: sc into alu, gu, aldiag ----
    for (int i = 0; i < n; ++i) {
        for (int j = i + 1 + tid; j < n; j += NTHREADS) {
            const float* p = lg + ((size_t)i * L + j) * 2;
            float v = lse2(p[0], p[1]);
            int id = idxu(i, j);
            alu[id] = v; gu[id] = v;
        }
    }
    if (tid < n) {
        const float* p = lg + ((size_t)tid * L + tid) * 2;
        aldiag[tid] = lse2(p[0], p[1]);
    }
    __syncthreads();

    const int c2 = tid >> 1;   // cell index within diagonal
    const int h  = tid & 1;    // half (2 threads per cell)

    // ---- inside: widths 1..n-1, alpha[i,j] = sc + LSE_m(alpha[i,m] + alpha[m+1,j]) ----
    for (int w = 1; w < n; ++w) {
        if (c2 < n - w) {
            int i = c2, j = i + w;
            float mrun = -FLT_MAX, srun = 0.0f;
            for (int m = i + h; m < j; m += 2) {
                float left  = (m == i)     ? aldiag[i] : alu[idxu(i, m)];
                float right = (m + 1 == j) ? aldiag[j] : alu[idxu(m + 1, j)];
                float v = left + right;
                float nm = fmaxf(mrun, v);
                srun = srun * __expf(mrun - nm) + __expf(v - nm);
                mrun = nm;
            }
            float om = __shfl_xor(mrun, 1);
            float os = __shfl_xor(srun, 1);
            if (h == 0) {
                float M = fmaxf(mrun, om);
                float S = srun * __expf(mrun - M) + os * __expf(om - M);
                int id = idxu(i, j);
                alu[id] = alu[id] + M + __logf(S);  // own slot still holds sc
            }
        }
        __syncthreads();
    }

    const float logZ = alu[idxu(0, n - 1)];

    // ---- outside: widths n-2..1, gamma[i,j] = sc[i,j] + LSE(parent terms) ----
    for (int w = n - 2; w >= 1; --w) {
        if (c2 < n - w) {
            int i = c2, j = i + w;
            int nt1 = n - 1 - j;        // left-child terms: k = j+1..n-1
            int nt  = nt1 + i;          // + right-child terms: k = 0..i-1
            float mrun = -FLT_MAX, srun = 0.0f;
            for (int t = h; t < nt; t += 2) {
                float v;
                if (t < nt1) {
                    int k = j + 1 + t;
                    float ar = (k == j + 1) ? aldiag[k] : alu[idxu(j + 1, k)];
                    v = gu[idxu(i, k)] + ar;
                } else {
                    int k = t - nt1;
                    float al_ = (k == i - 1) ? aldiag[k] : alu[idxu(k, i - 1)];
                    v = gu[idxu(k, j)] + al_;
                }
                float nm = fmaxf(mrun, v);
                srun = srun * __expf(mrun - nm) + __expf(v - nm);
                mrun = nm;
            }
            float om = __shfl_xor(mrun, 1);
            float os = __shfl_xor(srun, 1);
            if (h == 0) {
                float M = fmaxf(mrun, om);
                float S = srun * __expf(mrun - M) + os * __expf(om - M);
                int id = idxu(i, j);
                gu[id] = gu[id] + M + __logf(S);    // own slot still holds sc
            }
        }
        __syncthreads();
    }

    // ---- fused w=0 outside + diagonal loss, then strict-upper loss ----
    const int* si = spans_ind + mbase;
    double local = 0.0;

    if (c2 < n) {
        int i = c2;
        int nt1 = n - 1 - i;
        int nt  = n - 1;
        float mrun = -FLT_MAX, srun = 0.0f;
        for (int t = h; t < nt; t += 2) {
            float v;
            if (t < nt1) {
                int k = i + 1 + t;
                float ar = (k == i + 1) ? aldiag[k] : alu[idxu(i + 1, k)];
                v = gu[idxu(i, k)] + ar;
            } else {
                int k = t - nt1;
                float al_ = (k == i - 1) ? aldiag[k] : alu[idxu(k, i - 1)];
                v = gu[idxu(k, i)] + al_;
            }
            float nm = fmaxf(mrun, v);
            srun = srun * __expf(mrun - nm) + __expf(v - nm);
            mrun = nm;
        }
        float om = __shfl_xor(mrun, 1);
        float os = __shfl_xor(srun, 1);
        if (h == 0) {
            float M = fmaxf(mrun, om);
            float S = srun * __expf(mrun - M) + os * __expf(om - M);
            float beta_ii = M + __logf(S);
            const float* p = lg + ((size_t)i * L + i) * 2;
            int ind = si[i * L + i];
            float lc = (ind == 2) ? p[1] : p[0];
            // log marg = alpha_ii + beta_ii - logZ + l_c - sc_ii; alpha_ii == sc_ii
            float logm = beta_ii - logZ + lc;
            local += (double)fmaxf(logm, LOGMIN);
        }
    }

    for (int i = 0; i < n; ++i) {
        for (int j = i + 1 + tid; j < n; j += NTHREADS) {
            const float* p = lg + ((size_t)i * L + j) * 2;
            float a = p[0], c = p[1];
            float sc = lse2(a, c);
            int ind = si[i * L + j];
            float lc = (ind == 2) ? c : a;
            int id = idxu(i, j);
            // log marg = alpha + (gamma - sc) - logZ + l_c - sc
            float logm = alu[id] + gu[id] - logZ + lc - 2.0f * sc;
            local += (double)fmaxf(logm, LOGMIN);
        }
    }

    // wave reduce + one atomic per wave
    for (int off = 32; off > 0; off >>= 1)
        local += __shfl_down(local, off);
    if ((tid & 63) == 0) atomicAdd(&ws[0], local);
    if (tid == 0) atomicAdd(&ws[1], (double)n);
}

// ================= Kernel B: masked BCE sums for ph and pt =================
__global__ __launch_bounds__(256) void bce_kernel(
    const float* __restrict__ ph, const float* __restrict__ pt,
    const int* __restrict__ ph_ind, const int* __restrict__ pt_ind,
    const void* __restrict__ maskarc, double* __restrict__ ws)
{
    __shared__ double sred[12];
    const int mode = mask_mode(maskarc);
    const int tot = NB * L * L;
    double sph = 0.0, spt = 0.0, cnt = 0.0;
    for (int idx = blockIdx.x * blockDim.x + threadIdx.x; idx < tot;
         idx += gridDim.x * blockDim.x) {
        if (mask_at(maskarc, mode, idx)) {
            float x = ph[idx]; float y = (float)ph_ind[idx];
            sph += (double)(fmaxf(x, 0.0f) - x * y + log1pf(__expf(-fabsf(x))));
            x = pt[idx]; y = (float)pt_ind[idx];
            spt += (double)(fmaxf(x, 0.0f) - x * y + log1pf(__expf(-fabsf(x))));
            cnt += 1.0;
        }
    }
    for (int off = 32; off > 0; off >>= 1) {
        sph += __shfl_down(sph, off);
        spt += __shfl_down(spt, off);
        cnt += __shfl_down(cnt, off);
    }
    int wid = threadIdx.x >> 6, lane = threadIdx.x & 63;
    if (lane == 0) { sred[wid * 3] = sph; sred[wid * 3 + 1] = spt; sred[wid * 3 + 2] = cnt; }
    __syncthreads();
    if (threadIdx.x == 0) {
        double a = 0, bb = 0, c = 0;
        for (int k = 0; k < 4; ++k) { a += sred[k * 3]; bb += sred[k * 3 + 1]; c += sred[k * 3 + 2]; }
        atomicAdd(&ws[2], a); atomicAdd(&ws[3], bb); atomicAdd(&ws[4], c);
    }
}

// ================= Kernel C: finalize =================
__global__ void finalize_kernel(const double* __restrict__ ws, float* __restrict__ out) {
    double loss_spans = -ws[0] / ws[1];
    double bce = (ws[2] + ws[3]) / ws[4];
    out[0] = (float)(0.5 * loss_spans + 0.5 * bce);
}

extern "C" void kernel_launch(void* const* d_in, const int* in_sizes, int n_in,
                              void* d_out, int out_size, void* d_ws, size_t ws_size,
                              hipStream_t stream) {
    (void)in_sizes; (void)n_in; (void)out_size; (void)ws_size;
    const float* span_logits = (const float*)d_in[0];
    const float* ph          = (const float*)d_in[1];
    const float* pt          = (const float*)d_in[2];
    /* d_in[3] = ph_arc: unused by reference */
    const int*   spans_ind   = (const int*)d_in[4];
    const int*   ph_ind      = (const int*)d_in[5];
    const int*   pt_ind      = (const int*)d_in[6];
    const void*  maskspan    = d_in[7];
    const void*  maskarc     = d_in[8];
    double* ws = (double*)d_ws;
    float* out = (float*)d_out;

    hipMemsetAsync(d_ws, 0, 5 * sizeof(double), stream);
    hipLaunchKernelGGL(tree_dp_kernel, dim3(NB), dim3(NTHREADS), 0, stream,
                       span_logits, spans_ind, maskspan, ws);
    hipLaunchKernelGGL(bce_kernel, dim3(128), dim3(256), 0, stream,
                       ph, pt, ph_ind, pt_ind, maskarc, ws);
    hipLaunchKernelGGL(finalize_kernel, dim3(1), dim3(1), 0, stream, ws, out);
}

// Round 2
// 636.835 us; speedup vs baseline: 2.2911x; 2.2911x over previous
//
#include <hip/hip_runtime.h>
#include <hip/hip_bf16.h>
#include <float.h>

#define NB 32
#define L 128
#define NT 512
#define LOGMIN -87.49823f  /* ln(1e-38) */

// ---- mask dtype runtime detection (element [0] is guaranteed true: lens >= 64) ----
__device__ __forceinline__ int mask_mode(const void* p) {
    unsigned int v = ((const unsigned int*)p)[0];
    if (v == 1u) return 1;            // int32 0/1 storage
    if (v == 0x3F800000u) return 2;   // float32 storage
    return 0;                         // byte storage
}
__device__ __forceinline__ bool mask_at(const void* p, int mode, int idx) {
    if (mode == 1) return ((const int*)p)[idx] != 0;
    if (mode == 2) return ((const float*)p)[idx] != 0.0f;
    return ((const unsigned char*)p)[idx] != 0;
}

// triangle-with-diagonal layout: element (i,j), i<=j, at rowstart(i) + (j-i)
// rowstart(i) = sum_{k<i} (L-k) = i*L - i*(i-1)/2 ; total = L*(L+1)/2 = 8256
__device__ __forceinline__ int rowstart(int i) {
    return i * L - ((i * (i - 1)) >> 1);
}

__device__ __forceinline__ float lse2(float a, float b) {
    return fmaxf(a, b) + log1pf(__expf(-fabsf(a - b)));
}

// online-LSE accumulate one term
__device__ __forceinline__ void lse_acc(float v, float& m, float& s) {
    float nm = fmaxf(m, v);
    s = s * __expf(m - nm) + __expf(v - nm);
    m = nm;
}
// merge two (m,s) states into the first
__device__ __forceinline__ void lse_merge(float& m1, float& s1, float m2, float s2) {
    float M = fmaxf(m1, m2);
    s1 = s1 * __expf(m1 - M) + s2 * __expf(m2 - M);
    m1 = M;
}

// ================= Kernel A: per-batch inside/outside DP + span loss =================
__global__ __launch_bounds__(NT) void tree_dp_kernel(
    const float* __restrict__ logits,   // [B,L,L,2]
    const int*   __restrict__ spans_ind,// [B,L,L]
    const void*  __restrict__ maskspan, // [B,L,L] bool
    double*      __restrict__ ws)
{
    __shared__ float A[L * (L + 1) / 2];  // sc -> alpha (in place)
    __shared__ float G[L * (L + 1) / 2];  // sc -> gamma = sc + beta (in place)

    const int b   = blockIdx.x;
    const int tid = threadIdx.x;
    const int mbase = b * L * L;
    const int mode = mask_mode(maskspan);

    int pred = (tid < L) && mask_at(maskspan, mode, mbase + tid);
    const int n = __syncthreads_count(pred);

    const float* lg = logits + (size_t)b * L * L * 2;

    // ---- init: sc into A and G over the upper triangle (incl diagonal) ----
    for (int e = tid; e < L * L; e += NT) {
        int i = e >> 7, j = e & (L - 1);
        if (i <= j && j < n) {
            const float* p = lg + (size_t)e * 2;
            float v = lse2(p[0], p[1]);
            int id = rowstart(i) + (j - i);
            A[id] = v; G[id] = v;
        }
    }
    __syncthreads();

    // ---- inside: widths 1..n-1 ----
    for (int w = 1; w < n; ++w) {
        int c = n - w;                       // cells on this diagonal
        int q = NT / c;                      // >= 4
        int lt = (q >= 64) ? 6 : (31 - __clz(q));
        int T = 1 << lt;
        int cell = tid >> lt;
        int sub = tid & (T - 1);
        if (cell < c) {
            int i = cell;
            int baseL = rowstart(i);         // left terms: A[baseL + t], t in [0,w)
            float m0 = -FLT_MAX, s0 = 0.0f, m1 = -FLT_MAX, s1 = 0.0f;
            int t = sub;
            for (; t + T < w; t += 2 * T) {
                int t2 = t + T;
                int r0 = i + t + 1, r1 = i + t2 + 1;
                float v0 = A[baseL + t]  + A[rowstart(r0) + (w - 1 - t)];
                float v1 = A[baseL + t2] + A[rowstart(r1) + (w - 1 - t2)];
                lse_acc(v0, m0, s0);
                lse_acc(v1, m1, s1);
            }
            if (t < w) {
                float v0 = A[baseL + t] + A[rowstart(i + t + 1) + (w - 1 - t)];
                lse_acc(v0, m0, s0);
            }
            lse_merge(m0, s0, m1, s1);
            for (int off = T >> 1; off > 0; off >>= 1) {
                float mo = __shfl_xor(m0, off);
                float so = __shfl_xor(s0, off);
                lse_merge(m0, s0, mo, so);
            }
            if (sub == 0) {
                int id = baseL + w;
                A[id] = A[id] + m0 + __logf(s0);   // slot still holds sc
            }
        }
        __syncthreads();
    }

    const float logZ = A[n - 1];   // alpha[0, n-1]

    // ---- outside: widths n-2..1, G[i,j] = sc + LSE(parent terms) ----
    for (int w = n - 2; w >= 1; --w) {
        int c = n - w;
        int q = NT / c;
        int lt = (q >= 64) ? 6 : (31 - __clz(q));
        int T = 1 << lt;
        int cell = tid >> lt;
        int sub = tid & (T - 1);
        if (cell < c) {
            int i = cell, j = i + w;
            int nt1 = n - 1 - j;             // group1: k = j+1 .. n-1
            int nt  = nt1 + i;               // + group2: k = 0 .. i-1
            int gbase = rowstart(i) + w + 1; // G[i, j+1+t]
            int abase = rowstart(j + 1);     // A[j+1, j+1+t]
            float m0 = -FLT_MAX, s0 = 0.0f, m1 = -FLT_MAX, s1 = 0.0f;
            int t = sub;
            for (; t + T < nt; t += 2 * T) {
                int t2 = t + T;
                float v0, v1;
                if (t < nt1) v0 = G[gbase + t] + A[abase + t];
                else { int k = t - nt1; int rk = rowstart(k);
                       v0 = G[rk + (j - k)] + A[rk + (i - 1 - k)]; }
                if (t2 < nt1) v1 = G[gbase + t2] + A[abase + t2];
                else { int k = t2 - nt1; int rk = rowstart(k);
                       v1 = G[rk + (j - k)] + A[rk + (i - 1 - k)]; }
                lse_acc(v0, m0, s0);
                lse_acc(v1, m1, s1);
            }
            if (t < nt) {
                float v0;
                if (t < nt1) v0 = G[gbase + t] + A[abase + t];
                else { int k = t - nt1; int rk = rowstart(k);
                       v0 = G[rk + (j - k)] + A[rk + (i - 1 - k)]; }
                lse_acc(v0, m0, s0);
            }
            lse_merge(m0, s0, m1, s1);
            for (int off = T >> 1; off > 0; off >>= 1) {
                float mo = __shfl_xor(m0, off);
                float so = __shfl_xor(s0, off);
                lse_merge(m0, s0, mo, so);
            }
            if (sub == 0) {
                int id = rowstart(i) + w;
                G[id] = G[id] + m0 + __logf(s0);   // slot still holds sc
            }
        }
        __syncthreads();
    }

    // ---- fused w=0 outside (beta_ii) + diagonal loss ----
    const int* si = spans_ind + mbase;
    double local = 0.0;
    {
        int c = n;
        int q = NT / c;
        int lt = (q >= 64) ? 6 : (31 - __clz(q));
        int T = 1 << lt;
        int cell = tid >> lt;
        int sub = tid & (T - 1);
        if (cell < c) {
            int i = cell;
            int nt1 = n - 1 - i;
            int nt  = n - 1;
            int gbase = rowstart(i) + 1;
            int abase = rowstart(i + 1);     // only touched when nt1 > 0
            float m0 = -FLT_MAX, s0 = 0.0f, m1 = -FLT_MAX, s1 = 0.0f;
            int t = sub;
            for (; t + T < nt; t += 2 * T) {
                int t2 = t + T;
                float v0, v1;
                if (t < nt1) v0 = G[gbase + t] + A[abase + t];
                else { int k = t - nt1; int rk = rowstart(k);
                       v0 = G[rk + (i - k)] + A[rk + (i - 1 - k)]; }
                if (t2 < nt1) v1 = G[gbase + t2] + A[abase + t2];
                else { int k = t2 - nt1; int rk = rowstart(k);
                       v1 = G[rk + (i - k)] + A[rk + (i - 1 - k)]; }
                lse_acc(v0, m0, s0);
                lse_acc(v1, m1, s1);
            }
            if (t < nt) {
                float v0;
                if (t < nt1) v0 = G[gbase + t] + A[abase + t];
                else { int k = t - nt1; int rk = rowstart(k);
                       v0 = G[rk + (i - k)] + A[rk + (i - 1 - k)]; }
                lse_acc(v0, m0, s0);
            }
            lse_merge(m0, s0, m1, s1);
            for (int off = T >> 1; off > 0; off >>= 1) {
                float mo = __shfl_xor(m0, off);
                float so = __shfl_xor(s0, off);
                lse_merge(m0, s0, mo, so);
            }
            if (sub == 0) {
                float beta_ii = m0 + __logf(s0);
                const float* p = lg + ((size_t)i * L + i) * 2;
                int ind = si[i * L + i];
                float lc = (ind == 2) ? p[1] : p[0];
                // log marg = alpha_ii + beta_ii - logZ + l_c - sc_ii; alpha_ii == sc_ii
                float logm = beta_ii - logZ + lc;
                local += (double)fmaxf(logm, LOGMIN);
            }
        }
    }

    // ---- strict-upper loss ----
    for (int e = tid; e < L * L; e += NT) {
        int i = e >> 7, j = e & (L - 1);
        if (i < j && j < n) {
            const float* p = lg + (size_t)e * 2;
            float a = p[0], cc = p[1];
            float sc = lse2(a, cc);
            int ind = si[e];
            float lc = (ind == 2) ? cc : a;
            int id = rowstart(i) + (j - i);
            // log marg = alpha + (gamma - sc) - logZ + l_c - sc
            float logm = A[id] + G[id] - logZ + lc - 2.0f * sc;
            local += (double)fmaxf(logm, LOGMIN);
        }
    }

    // wave reduce + one atomic per wave
    for (int off = 32; off > 0; off >>= 1)
        local += __shfl_down(local, off);
    if ((tid & 63) == 0) atomicAdd(&ws[0], local);
    if (tid == 0) atomicAdd(&ws[1], (double)n);
}

// ================= Kernel B: masked BCE sums for ph and pt =================
__global__ __launch_bounds__(256) void bce_kernel(
    const float* __restrict__ ph, const float* __restrict__ pt,
    const int* __restrict__ ph_ind, const int* __restrict__ pt_ind,
    const void* __restrict__ maskarc, double* __restrict__ ws)
{
    __shared__ double sred[12];
    const int mode = mask_mode(maskarc);
    const int tot = NB * L * L;
    double sph = 0.0, spt = 0.0, cnt = 0.0;
    for (int idx = blockIdx.x * blockDim.x + threadIdx.x; idx < tot;
         idx += gridDim.x * blockDim.x) {
        if (mask_at(maskarc, mode, idx)) {
            float x = ph[idx]; float y = (float)ph_ind[idx];
            sph += (double)(fmaxf(x, 0.0f) - x * y + log1pf(__expf(-fabsf(x))));
            x = pt[idx]; y = (float)pt_ind[idx];
            spt += (double)(fmaxf(x, 0.0f) - x * y + log1pf(__expf(-fabsf(x))));
            cnt += 1.0;
        }
    }
    for (int off = 32; off > 0; off >>= 1) {
        sph += __shfl_down(sph, off);
        spt += __shfl_down(spt, off);
        cnt += __shfl_down(cnt, off);
    }
    int wid = threadIdx.x >> 6, lane = threadIdx.x & 63;
    if (lane == 0) { sred[wid * 3] = sph; sred[wid * 3 + 1] = spt; sred[wid * 3 + 2] = cnt; }
    __syncthreads();
    if (threadIdx.x == 0) {
        double a = 0, bb = 0, c = 0;
        for (int k = 0; k < 4; ++k) { a += sred[k * 3]; bb += sred[k * 3 + 1]; c += sred[k * 3 + 2]; }
        atomicAdd(&ws[2], a); atomicAdd(&ws[3], bb); atomicAdd(&ws[4], c);
    }
}

// ================= Kernel C: finalize =================
__global__ void finalize_kernel(const double* __restrict__ ws, float* __restrict__ out) {
    double loss_spans = -ws[0] / ws[1];
    double bce = (ws[2] + ws[3]) / ws[4];
    out[0] = (float)(0.5 * loss_spans + 0.5 * bce);
}

extern "C" void kernel_launch(void* const* d_in, const int* in_sizes, int n_in,
                              void* d_out, int out_size, void* d_ws, size_t ws_size,
                              hipStream_t stream) {
    (void)in_sizes; (void)n_in; (void)out_size; (void)ws_size;
    const float* span_logits = (const float*)d_in[0];
    const float* ph          = (const float*)d_in[1];
    const float* pt          = (const float*)d_in[2];
    /* d_in[3] = ph_arc: unused by reference */
    const int*   spans_ind   = (const int*)d_in[4];
    const int*   ph_ind      = (const int*)d_in[5];
    const int*   pt_ind      = (const int*)d_in[6];
    const void*  maskspan    = d_in[7];
    const void*  maskarc     = d_in[8];
    double* ws = (double*)d_ws;
    float* out = (float*)d_out;

    hipMemsetAsync(d_ws, 0, 5 * sizeof(double), stream);
    hipLaunchKernelGGL(tree_dp_kernel, dim3(NB), dim3(NT), 0, stream,
                       span_logits, spans_ind, maskspan, ws);
    hipLaunchKernelGGL(bce_kernel, dim3(128), dim3(256), 0, stream,
                       ph, pt, ph_ind, pt_ind, maskarc, ws);
    hipLaunchKernelGGL(finalize_kernel, dim3(1), dim3(1), 0, stream, ws, out);
}

// Round 3
// 479.508 us; speedup vs baseline: 3.0429x; 1.3281x over previous
//
#include <hip/hip_runtime.h>
#include <hip/hip_bf16.h>
#include <float.h>

#define NB 32
#define NBCE 32
#define L 128
#define NT 1024
#define LOGMIN -87.49823f  /* ln(1e-38) */

// ---- mask dtype runtime detection (element [0] is guaranteed true: lens >= 64) ----
__device__ __forceinline__ int mask_mode(const void* p) {
    unsigned int v = ((const unsigned int*)p)[0];
    if (v == 1u) return 1;            // int32 0/1 storage
    if (v == 0x3F800000u) return 2;   // float32 storage
    return 0;                         // byte storage
}
__device__ __forceinline__ bool mask_at(const void* p, int mode, int idx) {
    if (mode == 1) return ((const int*)p)[idx] != 0;
    if (mode == 2) return ((const float*)p)[idx] != 0.0f;
    return ((const unsigned char*)p)[idx] != 0;
}

// triangle-with-diagonal layout: (i,j), i<=j, at rowstart(i) + (j-i); total 8256
__device__ __forceinline__ int rowstart(int i) { return i * L - ((i * (i - 1)) >> 1); }

__device__ __forceinline__ float lse2(float a, float b) {
    return fmaxf(a, b) + log1pf(__expf(-fabsf(a - b)));
}

// ---- DPP butterfly reduce within aligned subgroups of 8 or 16 lanes ----
// masks {1,2,7} generate all of 0..7; adding {15} generates 0..15.
template<int C>
__device__ __forceinline__ float dppf(float x) {
    return __int_as_float(__builtin_amdgcn_mov_dpp(__float_as_int(x), C, 0xF, 0xF, true));
}
template<int T>
__device__ __forceinline__ float bfly_max(float x) {
    x = fmaxf(x, dppf<0xB1>(x));   // quad_perm(1,0,3,2): lane^1
    x = fmaxf(x, dppf<0x4E>(x));   // quad_perm(2,3,0,1): lane^2
    x = fmaxf(x, dppf<0x141>(x));  // row_half_mirror:    lane^7
    if (T == 16) x = fmaxf(x, dppf<0x140>(x)); // row_mirror: lane^15
    return x;
}
template<int T>
__device__ __forceinline__ float bfly_add(float x) {
    x += dppf<0xB1>(x);
    x += dppf<0x4E>(x);
    x += dppf<0x141>(x);
    if (T == 16) x += dppf<0x140>(x);
    return x;
}

// two-pass (max, then independent exps) LSE over nterm terms split across T lanes,
// contiguous chunk of NU terms per lane (left operands -> mergeable ds_read2)
template<int T, int NU, typename F>
__device__ __forceinline__ float lse_reduce(int sub, int nterm, F&& term) {
    float v[NU];
    const int base = sub * NU;
#pragma unroll
    for (int k = 0; k < NU; ++k) {
        int t = base + k;
        int tc = t < nterm ? t : nterm - 1;
        float val = term(tc);
        v[k] = (t < nterm) ? val : -FLT_MAX;
    }
    float M0 = v[0], M1 = (NU > 1) ? v[1] : -FLT_MAX;
#pragma unroll
    for (int k = 2; k < NU; k += 2) {
        M0 = fmaxf(M0, v[k]);
        if (k + 1 < NU) M1 = fmaxf(M1, v[k + 1]);
    }
    float M = bfly_max<T>(fmaxf(M0, M1));
    float s0 = 0.f, s1 = 0.f;
#pragma unroll
    for (int k = 0; k < NU; k += 2) {
        s0 += __expf(v[k] - M);                 // padded lanes: exp(-huge) = 0
        if (k + 1 < NU) s1 += __expf(v[k + 1] - M);
    }
    float s = bfly_add<T>(s0 + s1);
    return M + __logf(s);
}

// ================= fused kernel: blocks [0,NB) = per-batch DP; [NB,NB+NBCE) = BCE =================
__global__ __launch_bounds__(NT, 1) void tree_dp_kernel(
    const float* __restrict__ logits,   // [B,L,L,2]
    const int*   __restrict__ spans_ind,// [B,L,L]
    const void*  __restrict__ maskspan, // [B,L,L] bool
    const float* __restrict__ ph, const float* __restrict__ pt,
    const int* __restrict__ ph_ind, const int* __restrict__ pt_ind,
    const void* __restrict__ maskarc,
    double*      __restrict__ ws)
{
    const int tid = threadIdx.x;

    // ---------------- BCE blocks ----------------
    if (blockIdx.x >= NB) {
        const int mode = mask_mode(maskarc);
        const int tot = NB * L * L;
        double sph = 0.0, spt = 0.0, cnt = 0.0;
        for (int idx = (blockIdx.x - NB) * NT + tid; idx < tot; idx += NBCE * NT) {
            if (mask_at(maskarc, mode, idx)) {
                float x = ph[idx]; float y = (float)ph_ind[idx];
                sph += (double)(fmaxf(x, 0.0f) - x * y + log1pf(__expf(-fabsf(x))));
                x = pt[idx]; y = (float)pt_ind[idx];
                spt += (double)(fmaxf(x, 0.0f) - x * y + log1pf(__expf(-fabsf(x))));
                cnt += 1.0;
            }
        }
        for (int off = 32; off > 0; off >>= 1) {
            sph += __shfl_down(sph, off);
            spt += __shfl_down(spt, off);
            cnt += __shfl_down(cnt, off);
        }
        if ((tid & 63) == 0) {
            atomicAdd(&ws[2], sph); atomicAdd(&ws[3], spt); atomicAdd(&ws[4], cnt);
        }
        return;
    }

    // ---------------- DP blocks ----------------
    __shared__ float A[L * (L + 1) / 2];  // sc -> alpha (in place)
    __shared__ float G[L * (L + 1) / 2];  // sc -> gamma = sc + beta (in place)

    const int b = blockIdx.x;
    const int mbase = b * L * L;
    const int mode = mask_mode(maskspan);

    int pred = (tid < L) && mask_at(maskspan, mode, mbase + tid);
    const int n = __syncthreads_count(pred);

    const float* lg = logits + (size_t)b * L * L * 2;

    // ---- init: sc into A and G over upper triangle (incl diagonal) ----
    for (int e = tid; e < L * L; e += NT) {
        int i = e >> 7, j = e & (L - 1);
        if (i <= j && j < n) {
            const float* p = lg + (size_t)e * 2;
            float v = lse2(p[0], p[1]);
            int id = rowstart(i) + (j - i);
            A[id] = v; G[id] = v;
        }
    }
    __syncthreads();

    // ---- inside: widths 1..n-1 ----
    for (int w = 1; w < n; ++w) {
        int c = n - w;
        if (c > 64) {                       // T=8, terms = w <= 63
            int cell = tid >> 3, sub = tid & 7;
            if (cell < c) {
                int i = cell, baseL = rowstart(i);
                float r = lse_reduce<8, 8>(sub, w, [&](int t) {
                    return A[baseL + t] + A[rowstart(i + t + 1) + (w - 1 - t)];
                });
                if (sub == 0) { int id = baseL + w; A[id] += r; }  // slot holds sc
            }
        } else {                            // T=16, terms = w <= 127
            int cell = tid >> 4, sub = tid & 15;
            if (cell < c) {
                int i = cell, baseL = rowstart(i);
                float r = lse_reduce<16, 8>(sub, w, [&](int t) {
                    return A[baseL + t] + A[rowstart(i + t + 1) + (w - 1 - t)];
                });
                if (sub == 0) { int id = baseL + w; A[id] += r; }
            }
        }
        __syncthreads();
    }

    const float logZ = A[n - 1];   // alpha[0, n-1]

    // ---- outside: widths n-2..1; per-cell terms = n-1-w ----
    for (int w = n - 2; w >= 1; --w) {
        int c = n - w, nt = n - 1 - w;
        if (c > 64) {                       // nt in [64,126] -> T=8, NU=16
            int cell = tid >> 3, sub = tid & 7;
            if (cell < c) {
                int i = cell, j = i + w;
                int nt1 = n - 1 - j;
                int gb = rowstart(i), ab = rowstart(j + 1);
                float r = lse_reduce<8, 16>(sub, nt, [&](int t) {
                    if (t < nt1) return G[gb + w + 1 + t] + A[ab + t];
                    int k = t - nt1; int rk = rowstart(k);
                    return G[rk + (j - k)] + A[rk + (i - 1 - k)];
                });
                if (sub == 0) G[gb + w] += r;   // slot holds sc
            }
        } else {                            // nt <= 63 -> T=16, NU=4
            int cell = tid >> 4, sub = tid & 15;
            if (cell < c) {
                int i = cell, j = i + w;
                int nt1 = n - 1 - j;
                int gb = rowstart(i), ab = rowstart(j + 1);
                float r = lse_reduce<16, 4>(sub, nt, [&](int t) {
                    if (t < nt1) return G[gb + w + 1 + t] + A[ab + t];
                    int k = t - nt1; int rk = rowstart(k);
                    return G[rk + (j - k)] + A[rk + (i - 1 - k)];
                });
                if (sub == 0) G[gb + w] += r;
            }
        }
        __syncthreads();
    }

    // ---- fused w=0 outside (beta_ii) + diagonal loss ----
    const int* si = spans_ind + mbase;
    double local = 0.0;
    {
        int cell = tid >> 3, sub = tid & 7;       // T=8, nt = n-1 <= 127 -> NU=16
        if (cell < n) {
            int i = cell;
            int nt1 = n - 1 - i, nt = n - 1;
            int gb = rowstart(i), ab = rowstart(i + 1);
            float r = lse_reduce<8, 16>(sub, nt, [&](int t) {
                if (t < nt1) return G[gb + 1 + t] + A[ab + t];
                int k = t - nt1; int rk = rowstart(k);
                return G[rk + (i - k)] + A[rk + (i - 1 - k)];
            });
            if (sub == 0) {
                const float* p = lg + ((size_t)i * L + i) * 2;
                int ind = si[i * L + i];
                float lc = (ind == 2) ? p[1] : p[0];
                // log marg = alpha_ii + beta_ii - logZ + l_c - sc_ii; alpha_ii == sc_ii
                float logm = r - logZ + lc;
                local += (double)fmaxf(logm, LOGMIN);
            }
        }
    }

    // ---- strict-upper loss ----
    for (int e = tid; e < L * L; e += NT) {
        int i = e >> 7, j = e & (L - 1);
        if (i < j && j < n) {
            const float* p = lg + (size_t)e * 2;
            float a = p[0], cc = p[1];
            float sc = lse2(a, cc);
            int ind = si[e];
            float lc = (ind == 2) ? cc : a;
            int id = rowstart(i) + (j - i);
            // log marg = alpha + (gamma - sc) - logZ + l_c - sc
            float logm = A[id] + G[id] - logZ + lc - 2.0f * sc;
            local += (double)fmaxf(logm, LOGMIN);
        }
    }

    // wave reduce + one atomic per wave
    for (int off = 32; off > 0; off >>= 1)
        local += __shfl_down(local, off);
    if ((tid & 63) == 0) atomicAdd(&ws[0], local);
    if (tid == 0) atomicAdd(&ws[1], (double)n);
}

// ================= finalize =================
__global__ void finalize_kernel(const double* __restrict__ ws, float* __restrict__ out) {
    double loss_spans = -ws[0] / ws[1];
    double bce = (ws[2] + ws[3]) / ws[4];
    out[0] = (float)(0.5 * loss_spans + 0.5 * bce);
}

extern "C" void kernel_launch(void* const* d_in, const int* in_sizes, int n_in,
                              void* d_out, int out_size, void* d_ws, size_t ws_size,
                              hipStream_t stream) {
    (void)in_sizes; (void)n_in; (void)out_size; (void)ws_size;
    const float* span_logits = (const float*)d_in[0];
    const float* ph          = (const float*)d_in[1];
    const float* pt          = (const float*)d_in[2];
    /* d_in[3] = ph_arc: unused by reference */
    const int*   spans_ind   = (const int*)d_in[4];
    const int*   ph_ind      = (const int*)d_in[5];
    const int*   pt_ind      = (const int*)d_in[6];
    const void*  maskspan    = d_in[7];
    const void*  maskarc     = d_in[8];
    double* ws = (double*)d_ws;
    float* out = (float*)d_out;

    hipMemsetAsync(d_ws, 0, 5 * sizeof(double), stream);
    hipLaunchKernelGGL(tree_dp_kernel, dim3(NB + NBCE), dim3(NT), 0, stream,
                       span_logits, spans_ind, maskspan,
                       ph, pt, ph_ind, pt_ind, maskarc, ws);
    hipLaunchKernelGGL(finalize_kernel, dim3(1), dim3(1), 0, stream, ws, out);
}

// Round 4
// 323.673 us; speedup vs baseline: 4.5079x; 1.4815x over previous
//
#include <hip/hip_runtime.h>
#include <hip/hip_bf16.h>
#include <float.h>

#define NB 32
#define NBCE 32
#define L 128
#define NT 1024
#define R 132                      /* row stride of mirror-square (R = 4 mod 32) */
#define PAD 40                     /* tail pad: masked overreads stay in-bounds */
#define LOGMIN -87.49823f          /* ln(1e-38) */

// ---- mask dtype runtime detection (element [0] is guaranteed true: lens >= 64) ----
__device__ __forceinline__ int mask_mode(const void* p) {
    unsigned int v = ((const unsigned int*)p)[0];
    if (v == 1u) return 1;            // int32 0/1 storage
    if (v == 0x3F800000u) return 2;   // float32 storage
    return 0;                         // byte storage
}
__device__ __forceinline__ bool mask_at(const void* p, int mode, int idx) {
    if (mode == 1) return ((const int*)p)[idx] != 0;
    if (mode == 2) return ((const float*)p)[idx] != 0.0f;
    return ((const unsigned char*)p)[idx] != 0;
}

__device__ __forceinline__ float lse2(float a, float b) {
    return fmaxf(a, b) + log1pf(__expf(-fabsf(a - b)));
}

// ---- DPP butterfly reduce within aligned subgroups of 8 or 16 lanes ----
template<int C>
__device__ __forceinline__ float dppf(float x) {
    return __int_as_float(__builtin_amdgcn_mov_dpp(__float_as_int(x), C, 0xF, 0xF, true));
}
template<int T>
__device__ __forceinline__ float bfly_max(float x) {
    x = fmaxf(x, dppf<0xB1>(x));   // lane^1
    x = fmaxf(x, dppf<0x4E>(x));   // lane^2
    x = fmaxf(x, dppf<0x141>(x));  // row_half_mirror: lane^7 within 8
    if (T == 16) x = fmaxf(x, dppf<0x140>(x)); // row_mirror: ^15 within 16
    return x;
}
template<int T>
__device__ __forceinline__ float bfly_add(float x) {
    x += dppf<0xB1>(x);
    x += dppf<0x4E>(x);
    x += dppf<0x141>(x);
    if (T == 16) x += dppf<0x140>(x);
    return x;
}

// load terms t = sub + kk*T from two contiguous LDS streams; dynamic trip count.
// v[kk] left -FLT_MAX-safe; mloc updated with running max.
template<int T, int NUMAX>
__device__ __forceinline__ void load_terms(float* v, int sub, int nterm,
                                           const float* p1, const float* p2, float& mloc) {
    p1 += sub; p2 += sub;
#pragma unroll
    for (int kk = 0; kk < NUMAX; kk += 2) {
        if (kk * T >= nterm) break;
        const int o0 = kk * T, o1 = o0 + T;
        float a0 = p1[o0] + p2[o0];
        float a1 = p1[o1] + p2[o1];
        a0 = (sub + o0 < nterm) ? a0 : -FLT_MAX;
        a1 = (sub + o1 < nterm) ? a1 : -FLT_MAX;
        v[kk] = a0; v[kk + 1] = a1;
        mloc = fmaxf(mloc, fmaxf(a0, a1));
    }
}
template<int T, int NUMAX>
__device__ __forceinline__ void sum_exp(const float* v, int nterm, float M, float& s) {
#pragma unroll
    for (int kk = 0; kk < NUMAX; kk += 2) {
        if (kk * T >= nterm) break;
        s += __expf(v[kk] - M) + __expf(v[kk + 1] - M);
    }
}

// ================= fused kernel: blocks [0,NB) = per-batch DP; [NB,NB+NBCE) = BCE =================
__global__ __launch_bounds__(NT, 1) void tree_dp_kernel(
    const float* __restrict__ logits,   // [B,L,L,2]
    const int*   __restrict__ spans_ind,// [B,L,L]
    const void*  __restrict__ maskspan, // [B,L,L] bool
    const float* __restrict__ ph, const float* __restrict__ pt,
    const int* __restrict__ ph_ind, const int* __restrict__ pt_ind,
    const void* __restrict__ maskarc,
    double*      __restrict__ ws)
{
    const int tid = threadIdx.x;

    // ---------------- BCE blocks (no LDS use) ----------------
    if (blockIdx.x >= NB) {
        const int mode = mask_mode(maskarc);
        const int tot = NB * L * L;
        double sph = 0.0, spt = 0.0, cnt = 0.0;
        for (int idx = (blockIdx.x - NB) * NT + tid; idx < tot; idx += NBCE * NT) {
            if (mask_at(maskarc, mode, idx)) {
                float x = ph[idx]; float y = (float)ph_ind[idx];
                sph += (double)(fmaxf(x, 0.0f) - x * y + log1pf(__expf(-fabsf(x))));
                x = pt[idx]; y = (float)pt_ind[idx];
                spt += (double)(fmaxf(x, 0.0f) - x * y + log1pf(__expf(-fabsf(x))));
                cnt += 1.0;
            }
        }
        for (int off = 32; off > 0; off >>= 1) {
            sph += __shfl_down(sph, off);
            spt += __shfl_down(spt, off);
            cnt += __shfl_down(cnt, off);
        }
        if ((tid & 63) == 0) {
            atomicAdd(&ws[2], sph); atomicAdd(&ws[3], spt); atomicAdd(&ws[4], cnt);
        }
        return;
    }

    // ---------------- DP blocks ----------------
    // mirror-square: Am[i*R+j] == Am[j*R+i] == alpha[i,j] (i<=j). Same for Gm (gamma).
    __shared__ float Am[L * R + PAD];
    __shared__ float Gm[L * R + PAD];

    const int b = blockIdx.x;
    const int mbase = b * L * L;
    const int mode = mask_mode(maskspan);

    int pred = (tid < L) && mask_at(maskspan, mode, mbase + tid);
    const int n = __syncthreads_count(pred);

    const float* lg = logits + (size_t)b * L * L * 2;

    // ---- init: sc into both mirror halves of Am and Gm ----
    for (int e = tid; e < L * L; e += NT) {
        int i = e >> 7, j = e & (L - 1);
        if (i <= j && j < n) {
            const float* p = lg + (size_t)e * 2;
            float v = lse2(p[0], p[1]);
            Am[i * R + j] = v; Am[j * R + i] = v;
            Gm[i * R + j] = v; Gm[j * R + i] = v;
        }
    }
    __syncthreads();

    // ---- inside: widths 1..n-1 ----
    // alpha[i,j] = sc[i,j] + LSE_t( alpha[i,i+t] + alpha[i+1+t,j] ), t in [0,w)
    // left  stream: Am row i  cols i..        (contiguous)
    // right stream: Am row j (mirror) cols i+1.. (contiguous)
    for (int w = 1; w < n; ++w) {
        int c = n - w;
        if (c > 64) {                       // T=8, w <= 63 -> NUMAX 8
            int cell = tid >> 3, sub = tid & 7;
            if (cell < c) {
                int i = cell, j = i + w;
                float v[8]; float mloc = -FLT_MAX;
                load_terms<8, 8>(v, sub, w, &Am[i * R + i], &Am[j * R + i + 1], mloc);
                float M = bfly_max<8>(mloc);
                float s = 0.0f;
                sum_exp<8, 8>(v, w, M, s);
                float S = bfly_add<8>(s);
                if (sub == 0) {
                    float val = Am[i * R + j] + M + __logf(S);  // slot holds sc
                    Am[i * R + j] = val; Am[j * R + i] = val;
                }
            }
        } else {                            // T=16, w <= 127 -> NUMAX 8
            int cell = tid >> 4, sub = tid & 15;
            if (cell < c) {
                int i = cell, j = i + w;
                float v[8]; float mloc = -FLT_MAX;
                load_terms<16, 8>(v, sub, w, &Am[i * R + i], &Am[j * R + i + 1], mloc);
                float M = bfly_max<16>(mloc);
                float s = 0.0f;
                sum_exp<16, 8>(v, w, M, s);
                float S = bfly_add<16>(s);
                if (sub == 0) {
                    float val = Am[i * R + j] + M + __logf(S);
                    Am[i * R + j] = val; Am[j * R + i] = val;
                }
            }
        }
        __syncthreads();
    }

    const float logZ = Am[n - 1];   // alpha[0, n-1]

    // ---- outside: widths n-2..1 ----
    // gamma[i,j] = sc[i,j] + LSE( k>j: gamma[i,k]+alpha[j+1,k] ; k<i: gamma[k,j]+alpha[k,i-1] )
    // g1: Gm row i cols j+1..  +  Am row j+1 cols j+1..      (both contiguous)
    // g2: Gm row j (mirror) cols 0..  +  Am row i-1 (mirror) cols 0..  (both contiguous)
    for (int w = n - 2; w >= 1; --w) {
        int c = n - w;
        if (c > 64) {                       // T=8; nt1 <= 126, i <= 126 -> NUMAX 16
            int cell = tid >> 3, sub = tid & 7;
            if (cell < c) {
                int i = cell, j = i + w;
                int nt1 = n - 1 - j;
                float v1[16], v2[16]; float mloc = -FLT_MAX;
                load_terms<8, 16>(v1, sub, nt1, &Gm[i * R + j + 1], &Am[(j + 1) * R + j + 1], mloc);
                load_terms<8, 16>(v2, sub, i,   &Gm[j * R],         &Am[(i - 1) * R],         mloc);
                float M = bfly_max<8>(mloc);
                float s = 0.0f;
                sum_exp<8, 16>(v1, nt1, M, s);
                sum_exp<8, 16>(v2, i,   M, s);
                float S = bfly_add<8>(s);
                if (sub == 0) {
                    float val = Gm[i * R + j] + M + __logf(S);  // slot holds sc
                    Gm[i * R + j] = val; Gm[j * R + i] = val;
                }
            }
        } else {                            // T=16; nt1 <= 63, i <= 63 -> NUMAX 4
            int cell = tid >> 4, sub = tid & 15;
            if (cell < c) {
                int i = cell, j = i + w;
                int nt1 = n - 1 - j;
                float v1[4], v2[4]; float mloc = -FLT_MAX;
                load_terms<16, 4>(v1, sub, nt1, &Gm[i * R + j + 1], &Am[(j + 1) * R + j + 1], mloc);
                load_terms<16, 4>(v2, sub, i,   &Gm[j * R],         &Am[(i - 1) * R],         mloc);
                float M = bfly_max<16>(mloc);
                float s = 0.0f;
                sum_exp<16, 4>(v1, nt1, M, s);
                sum_exp<16, 4>(v2, i,   M, s);
                float S = bfly_add<16>(s);
                if (sub == 0) {
                    float val = Gm[i * R + j] + M + __logf(S);
                    Gm[i * R + j] = val; Gm[j * R + i] = val;
                }
            }
        }
        __syncthreads();
    }

    // ---- fused w=0 outside (beta_ii) + diagonal loss ----
    const int* si = spans_ind + mbase;
    double local = 0.0;
    {
        int cell = tid >> 3, sub = tid & 7;       // T=8; nt1 <= 127, i <= 127 -> NUMAX 16
        if (cell < n) {
            int i = cell;
            int nt1 = n - 1 - i;
            float v1[16], v2[16]; float mloc = -FLT_MAX;
            load_terms<8, 16>(v1, sub, nt1, &Gm[i * R + i + 1], &Am[(i + 1) * R + i + 1], mloc);
            load_terms<8, 16>(v2, sub, i,   &Gm[i * R],         &Am[(i - 1) * R],         mloc);
            float M = bfly_max<8>(mloc);
            float s = 0.0f;
            sum_exp<8, 16>(v1, nt1, M, s);
            sum_exp<8, 16>(v2, i,   M, s);
            float S = bfly_add<8>(s);
            if (sub == 0) {
                float beta_ii = M + __logf(S);
                const float* p = lg + ((size_t)i * L + i) * 2;
                int ind = si[i * L + i];
                float lc = (ind == 2) ? p[1] : p[0];
                // log marg = alpha_ii + beta_ii - logZ + l_c - sc_ii; alpha_ii == sc_ii
                float logm = beta_ii - logZ + lc;
                local += (double)fmaxf(logm, LOGMIN);
            }
        }
    }

    // ---- strict-upper loss ----
    for (int e = tid; e < L * L; e += NT) {
        int i = e >> 7, j = e & (L - 1);
        if (i < j && j < n) {
            const float* p = lg + (size_t)e * 2;
            float a = p[0], cc = p[1];
            float sc = lse2(a, cc);
            int ind = si[e];
            float lc = (ind == 2) ? cc : a;
            // log marg = alpha + (gamma - sc) - logZ + l_c - sc
            float logm = Am[i * R + j] + Gm[i * R + j] - logZ + lc - 2.0f * sc;
            local += (double)fmaxf(logm, LOGMIN);
        }
    }

    // wave reduce + one atomic per wave
    for (int off = 32; off > 0; off >>= 1)
        local += __shfl_down(local, off);
    if ((tid & 63) == 0) atomicAdd(&ws[0], local);
    if (tid == 0) atomicAdd(&ws[1], (double)n);
}

// ================= finalize =================
__global__ void finalize_kernel(const double* __restrict__ ws, float* __restrict__ out) {
    double loss_spans = -ws[0] / ws[1];
    double bce = (ws[2] + ws[3]) / ws[4];
    out[0] = (float)(0.5 * loss_spans + 0.5 * bce);
}

extern "C" void kernel_launch(void* const* d_in, const int* in_sizes, int n_in,
                              void* d_out, int out_size, void* d_ws, size_t ws_size,
                              hipStream_t stream) {
    (void)in_sizes; (void)n_in; (void)out_size; (void)ws_size;
    const float* span_logits = (const float*)d_in[0];
    const float* ph          = (const float*)d_in[1];
    const float* pt          = (const float*)d_in[2];
    /* d_in[3] = ph_arc: unused by reference */
    const int*   spans_ind   = (const int*)d_in[4];
    const int*   ph_ind      = (const int*)d_in[5];
    const int*   pt_ind      = (const int*)d_in[6];
    const void*  maskspan    = d_in[7];
    const void*  maskarc     = d_in[8];
    double* ws = (double*)d_ws;
    float* out = (float*)d_out;

    hipMemsetAsync(d_ws, 0, 5 * sizeof(double), stream);
    hipLaunchKernelGGL(tree_dp_kernel, dim3(NB + NBCE), dim3(NT), 0, stream,
                       span_logits, spans_ind, maskspan,
                       ph, pt, ph_ind, pt_ind, maskarc, ws);
    hipLaunchKernelGGL(finalize_kernel, dim3(1), dim3(1), 0, stream, ws, out);
}